// Round 1
// baseline (43.163 us; speedup 1.0000x reference)
//
#include <hip/hip_runtime.h>
#include <cfloat>

#define HH 800
#define WW 1024
#define NLOC 17064
#define BB 16
#define GG 48
#define NCLS 80
#define INF_A 100000000.0f

// Output section bases (in floats). Rows R = BB*NLOC = 273024.
#define LAB_BASE 0
#define REG_BASE 273024
#define TIND_BASE 1365120
#define ISIN_BASE 1638144

__global__ __launch_bounds__(256)
void count_kernel(const float* __restrict__ loc,
                  const float* __restrict__ boxes,
                  int* __restrict__ cnt) {
    const int bg = blockIdx.x;  // b*GG + g
    const float x1 = boxes[bg * 4 + 0];
    const float y1 = boxes[bg * 4 + 1];
    const float x2 = boxes[bg * 4 + 2];
    const float y2 = boxes[bg * 4 + 3];
    int c = 0;
    for (int j = threadIdx.x; j < NLOC; j += 256) {
        const float x = loc[2 * j];
        const float y = loc[2 * j + 1];
        const float l = x - x1, t = y - y1, r = x2 - x, btm = y2 - y;
        const float mn = fminf(fminf(l, t), fminf(r, btm));
        c += (mn > 0.0f) ? 1 : 0;
    }
#pragma unroll
    for (int o = 32; o > 0; o >>= 1) c += __shfl_down(c, o, 64);
    __shared__ int sred[4];
    const int lane = threadIdx.x & 63;
    const int wid = threadIdx.x >> 6;
    if (lane == 0) sred[wid] = c;
    __syncthreads();
    if (threadIdx.x == 0) cnt[bg] = sred[0] + sred[1] + sred[2] + sred[3];
}

__global__ __launch_bounds__(256)
void assign_kernel(const float* __restrict__ loc,
                   const float* __restrict__ boxes,
                   const int* __restrict__ cls,
                   const float* __restrict__ masks,
                   const int* __restrict__ cnt,
                   float* __restrict__ out) {
    const int b = blockIdx.y;
    const int j0 = blockIdx.x * 256 + threadIdx.x;

    __shared__ float sx1[GG], sy1[GG], sx2[GG], sy2[GG], sarea[GG];
    __shared__ int scls[GG], scnt[GG];
    __shared__ unsigned long long smask[256];  // final is_in * (label==0) bitmask per row
    __shared__ int srow[256];

    if (threadIdx.x < GG) {
        const int g = threadIdx.x;
        const float x1 = boxes[(b * GG + g) * 4 + 0];
        const float y1 = boxes[(b * GG + g) * 4 + 1];
        const float x2 = boxes[(b * GG + g) * 4 + 2];
        const float y2 = boxes[(b * GG + g) * 4 + 3];
        sx1[g] = x1; sy1[g] = y1; sx2[g] = x2; sy2[g] = y2;
        sarea[g] = (x2 - x1) * (y2 - y1);
        scls[g] = cls[b * GG + g];
        scnt[g] = cnt[b * GG + g];
    }
    __syncthreads();

    unsigned long long finmask = 0ull;
    int row = 0;
    if (j0 < NLOC) {
        int begv, nl, sv; float lov, hiv;
        if (j0 < 12800)      { begv = 0;     nl = 12800; sv = 8;   lov = -1.0f;  hiv = 64.0f; }
        else if (j0 < 16000) { begv = 12800; nl = 3200;  sv = 16;  lov = 64.0f;  hiv = 128.0f; }
        else if (j0 < 16800) { begv = 16000; nl = 800;   sv = 32;  lov = 128.0f; hiv = 256.0f; }
        else if (j0 < 17008) { begv = 16800; nl = 208;   sv = 64;  lov = 256.0f; hiv = 512.0f; }
        else                 { begv = 17008; nl = 56;    sv = 128; lov = 512.0f; hiv = INF_A; }

        const float x = loc[2 * j0];
        const float y = loc[2 * j0 + 1];
        int xi = (int)x; xi = min(max(xi, 0), WW - 1);
        int yi = (int)y; yi = min(max(yi, 0), HH - 1);
        const float mloc = masks[(size_t)b * (HH * WW) + (size_t)yi * WW + xi];
        const bool mpos = mloc > 0.0f;

        float best = FLT_MAX;
        int bi = 0;
        unsigned long long inmask = 0ull;
#pragma unroll 8
        for (int g = 0; g < GG; ++g) {
            const float l = x - sx1[g];
            const float t = y - sy1[g];
            const float r = sx2[g] - x;
            const float btm = sy2[g] - y;
            const float mn = fminf(fminf(l, t), fminf(r, btm));
            bool is_in = mn > 0.0f;
            if (scnt[g] > 1) is_in = is_in && mpos;
            const float mx = fmaxf(fmaxf(l, t), fmaxf(r, btm));
            const bool cared = (mx >= lov) && (mx <= hiv);
            const float la = (is_in && cared) ? sarea[g] : INF_A;
            if (la < best) { best = la; bi = g; }  // strict < == argmin first-occurrence
            if (is_in) inmask |= (1ull << g);
        }

        int label = scls[bi];
        if (best >= INF_A) label = NCLS;
        if (mloc == 0.0f) label = NCLS;

        row = BB * begv + b * nl + (j0 - begv);

        out[LAB_BASE + row] = (float)label;

        const float inv_s = 1.0f / (float)sv;  // exact power-of-2 reciprocal
        float4 rg;
        rg.x = (x - sx1[bi]) * inv_s;
        rg.y = (y - sy1[bi]) * inv_s;
        rg.z = (sx2[bi] - x) * inv_s;
        rg.w = (sy2[bi] - y) * inv_s;
        reinterpret_cast<float4*>(out + REG_BASE)[row] = rg;

        out[TIND_BASE + row] = (float)((bi + b * GG) * (mpos ? 1 : 0));

        finmask = (label == 0) ? inmask : 0ull;
    }
    smask[threadIdx.x] = finmask;
    srow[threadIdx.x] = row;
    __syncthreads();

    // Cooperative, coalesced write of the (nrows x 48) is_in section.
    const int blockstart = blockIdx.x * 256;
    const int nrows = min(256, NLOC - blockstart);
    for (int idx = threadIdx.x; idx < nrows * GG; idx += 256) {
        const int lr = idx / GG;
        const int g = idx - lr * GG;
        out[(size_t)ISIN_BASE + (size_t)srow[lr] * GG + g] =
            (float)((smask[lr] >> g) & 1ull);
    }
}

extern "C" void kernel_launch(void* const* d_in, const int* in_sizes, int n_in,
                              void* d_out, int out_size, void* d_ws, size_t ws_size,
                              hipStream_t stream) {
    const float* loc   = (const float*)d_in[0];
    const float* boxes = (const float*)d_in[1];
    const int*   cls   = (const int*)d_in[2];
    const float* masks = (const float*)d_in[3];
    float* out = (float*)d_out;
    int* cnt = (int*)d_ws;  // BB*GG ints = 3072 B of scratch

    count_kernel<<<BB * GG, 256, 0, stream>>>(loc, boxes, cnt);

    dim3 grid((NLOC + 255) / 256, BB);
    assign_kernel<<<grid, 256, 0, stream>>>(loc, boxes, cls, masks, cnt, out);
}

// Round 2
// 36.774 us; speedup vs baseline: 1.1737x; 1.1737x over previous
//
#include <hip/hip_runtime.h>
#include <cfloat>

#define HH 800
#define WW 1024
#define NLOC 17064
#define BB 16
#define GG 48
#define NCLS 80
#define INF_A 100000000.0f

// Output section bases (in floats). Rows R = BB*NLOC = 273024.
#define LAB_BASE 0
#define REG_BASE 273024
#define TIND_BASE 1365120
#define ISIN_BASE 1638144

__global__ __launch_bounds__(256)
void count_kernel(const float* __restrict__ loc,
                  const float* __restrict__ boxes,
                  int* __restrict__ cnt) {
    const int bg = blockIdx.x;  // b*GG + g
    const float4 bx = reinterpret_cast<const float4*>(boxes)[bg];
    const float2* __restrict__ lp = reinterpret_cast<const float2*>(loc);
    int c = 0;
    for (int j = threadIdx.x; j < NLOC; j += 256) {
        const float2 p = lp[j];
        const float mn = fminf(fminf(p.x - bx.x, p.y - bx.y),
                               fminf(bx.z - p.x, bx.w - p.y));
        c += (mn > 0.0f) ? 1 : 0;
    }
#pragma unroll
    for (int o = 32; o > 0; o >>= 1) c += __shfl_down(c, o, 64);
    __shared__ int sred[4];
    const int lane = threadIdx.x & 63;
    const int wid = threadIdx.x >> 6;
    if (lane == 0) sred[wid] = c;
    __syncthreads();
    if (threadIdx.x == 0) cnt[bg] = sred[0] + sred[1] + sred[2] + sred[3];
}

__global__ __launch_bounds__(256)
void assign_kernel(const float* __restrict__ loc,
                   const float* __restrict__ boxes,
                   const int* __restrict__ cls,
                   const float* __restrict__ masks,
                   const int* __restrict__ cnt,
                   float* __restrict__ out) {
    const int b = blockIdx.y;
    const int tid = threadIdx.x;
    const int blockstart = blockIdx.x * 256;
    const int j0 = blockstart + tid;

    __shared__ ulonglong2 sdat[256];  // {final is_in mask, row}

    // Block-uniform pointers -> scalar (s_load) path, no LDS staging needed.
    const float4* __restrict__ bbx = reinterpret_cast<const float4*>(boxes) + b * GG;
    const int* __restrict__ cntb = cnt + b * GG;

    unsigned long long finmask = 0ull;
    int row = 0;
    if (j0 < NLOC) {
        int begv, nl, sv; float lov, hiv;
        if (j0 < 12800)      { begv = 0;     nl = 12800; sv = 8;   lov = -1.0f;  hiv = 64.0f; }
        else if (j0 < 16000) { begv = 12800; nl = 3200;  sv = 16;  lov = 64.0f;  hiv = 128.0f; }
        else if (j0 < 16800) { begv = 16000; nl = 800;   sv = 32;  lov = 128.0f; hiv = 256.0f; }
        else if (j0 < 17008) { begv = 16800; nl = 208;   sv = 64;  lov = 256.0f; hiv = 512.0f; }
        else                 { begv = 17008; nl = 56;    sv = 128; lov = 512.0f; hiv = INF_A; }

        const float2 p = reinterpret_cast<const float2*>(loc)[j0];
        int xi = (int)p.x; xi = min(max(xi, 0), WW - 1);
        int yi = (int)p.y; yi = min(max(yi, 0), HH - 1);
        const float mloc = masks[(size_t)b * (HH * WW) + (size_t)yi * WW + xi];
        const bool mpos = mloc > 0.0f;

        float best = FLT_MAX;
        int bi = 0;
        // Descending g: shift-in mask build (constant shifts); `<=` keeps
        // first-occurrence (smallest g) argmin tie-break, values exact.
#pragma unroll 8
        for (int g = GG - 1; g >= 0; --g) {
            const float4 bx = bbx[g];     // uniform -> s_load_dwordx4
            const int cg = cntb[g];       // uniform -> s_load_dword
            const float l  = p.x - bx.x;
            const float t  = p.y - bx.y;
            const float r  = bx.z - p.x;
            const float bt = bx.w - p.y;
            const float mn = fminf(fminf(l, t), fminf(r, bt));
            const float mx = fmaxf(fmaxf(l, t), fmaxf(r, bt));
            const bool in = (mn > 0.0f) && (mpos || cg <= 1);
            const bool sel = in && (mx >= lov) && (mx <= hiv);
            const float area = (bx.z - bx.x) * (bx.w - bx.y);  // exact, matches ref
            const float la = sel ? area : INF_A;
            if (la <= best) { best = la; bi = g; }
            finmask = (finmask << 1) | (in ? 1ull : 0ull);
        }

        const float4 cb = bbx[bi];  // divergent gather of winning box (L1-hot)
        int label = (best >= INF_A || !mpos) ? NCLS : cls[b * GG + bi];

        row = BB * begv + b * nl + (j0 - begv);

        out[LAB_BASE + row] = (float)label;

        const float inv_s = 1.0f / (float)sv;  // exact pow2 reciprocal
        float4 rg;
        rg.x = (p.x - cb.x) * inv_s;
        rg.y = (p.y - cb.y) * inv_s;
        rg.z = (cb.z - p.x) * inv_s;
        rg.w = (cb.w - p.y) * inv_s;
        reinterpret_cast<float4*>(out + REG_BASE)[row] = rg;

        out[TIND_BASE + row] = (float)((bi + b * GG) * (mpos ? 1 : 0));

        if (label != 0) finmask = 0ull;
    }
    sdat[tid].x = finmask;
    sdat[tid].y = (unsigned long long)row;
    __syncthreads();

    // Coalesced float4 writes of the (nrows x 48) is_in section.
    const int nrows = min(256, NLOC - blockstart);
    const int n4 = nrows * 12;  // 12 float4 per row
    float4* __restrict__ outi = reinterpret_cast<float4*>(out + ISIN_BASE);
    for (int i4 = tid; i4 < n4; i4 += 256) {
        const int lr = i4 / 12;          // magic-mul division
        const int q = i4 - lr * 12;
        const ulonglong2 d = sdat[lr];   // one ds_read_b128 per 4 outputs
        const unsigned int bits = (unsigned int)(d.x >> (q * 4)) & 15u;
        float4 v;
        v.x = (bits & 1u) ? 1.0f : 0.0f;
        v.y = (bits & 2u) ? 1.0f : 0.0f;
        v.z = (bits & 4u) ? 1.0f : 0.0f;
        v.w = (bits & 8u) ? 1.0f : 0.0f;
        outi[(int)d.y * 12 + q] = v;
    }
}

extern "C" void kernel_launch(void* const* d_in, const int* in_sizes, int n_in,
                              void* d_out, int out_size, void* d_ws, size_t ws_size,
                              hipStream_t stream) {
    const float* loc   = (const float*)d_in[0];
    const float* boxes = (const float*)d_in[1];
    const int*   cls   = (const int*)d_in[2];
    const float* masks = (const float*)d_in[3];
    float* out = (float*)d_out;
    int* cnt = (int*)d_ws;  // BB*GG ints = 3072 B of scratch

    count_kernel<<<BB * GG, 256, 0, stream>>>(loc, boxes, cnt);

    dim3 grid((NLOC + 255) / 256, BB);
    assign_kernel<<<grid, 256, 0, stream>>>(loc, boxes, cls, masks, cnt, out);
}

// Round 3
// 24.722 us; speedup vs baseline: 1.7460x; 1.4875x over previous
//
#include <hip/hip_runtime.h>
#include <cfloat>

#define HH 800
#define WW 1024
#define NLOC 17064
#define BB 16
#define GG 48
#define NCLS 80
#define INF_A 100000000.0f

// Output section bases (in floats). Rows R = BB*NLOC = 273024.
#define LAB_BASE 0
#define REG_BASE 273024
#define TIND_BASE 1365120
#define ISIN_BASE 1638144

// #{i in [0,n): lo < i*s + hs < hi}, s = 1/inv a power of two, hs = s/2.
// Exact vs the brute-force fp32 comparisons (see analysis): strict ix > t
// <=> ix >= floor(t)+1 for ANY real t; strict ix < u <=> ix <= ceil(u)-1.
__device__ __forceinline__ int axis_count(float lo, float hi, float hs,
                                          float inv, int n) {
    int i0 = (int)floorf((lo - hs) * inv) + 1;
    i0 = max(i0, 0);
    int i1 = (int)ceilf((hi - hs) * inv) - 1;
    i1 = min(i1, n - 1);
    return max(0, i1 - i0 + 1);
}

__global__ __launch_bounds__(256)
void assign_kernel(const float* __restrict__ loc,
                   const float* __restrict__ boxes,
                   const int* __restrict__ cls,
                   const float* __restrict__ masks,
                   float* __restrict__ out) {
    const int b = blockIdx.y;
    const int tid = threadIdx.x;
    const int blockstart = blockIdx.x * 256;
    const int j0 = blockstart + tid;

    __shared__ ulonglong2 sdat[256];   // {final is_in mask, row}
    __shared__ unsigned int scm[2];    // per-image cnt>1 bitmask

    // Block-uniform pointer -> scalar (s_load) path for box reads in g-loop.
    const float4* __restrict__ bbx = reinterpret_cast<const float4*>(boxes) + b * GG;

    // --- closed-form per-box location count, wave 0 only (exact, see above) ---
    if (tid < 64) {
        bool many = false;
        if (tid < GG) {
            const float4 bx = bbx[tid];
            int total = 0;
            const int wl[5] = {128, 64, 32, 16, 8};
            const int hl[5] = {100, 50, 25, 13, 7};
#pragma unroll
            for (int l = 0; l < 5; ++l) {
                const float s = (float)(8 << l);
                const float hs = 0.5f * s;
                const float inv = 1.0f / s;
                total += axis_count(bx.x, bx.z, hs, inv, wl[l]) *
                         axis_count(bx.y, bx.w, hs, inv, hl[l]);
            }
            many = total > 1;
        }
        const unsigned long long m = __ballot(many);
        if (tid == 0) { scm[0] = (unsigned int)m; scm[1] = (unsigned int)(m >> 32); }
    }
    __syncthreads();
    // Broadcast mask into SGPRs: g-loop bit tests become free SALU ops.
    const unsigned int clo = __builtin_amdgcn_readfirstlane(scm[0]);
    const unsigned int chi = __builtin_amdgcn_readfirstlane(scm[1]);
    const unsigned long long cmask = ((unsigned long long)chi << 32) | clo;

    unsigned long long finmask = 0ull;
    int row = 0;
    if (j0 < NLOC) {
        int begv, nl, sv; float lov, hiv;
        if (j0 < 12800)      { begv = 0;     nl = 12800; sv = 8;   lov = -1.0f;  hiv = 64.0f; }
        else if (j0 < 16000) { begv = 12800; nl = 3200;  sv = 16;  lov = 64.0f;  hiv = 128.0f; }
        else if (j0 < 16800) { begv = 16000; nl = 800;   sv = 32;  lov = 128.0f; hiv = 256.0f; }
        else if (j0 < 17008) { begv = 16800; nl = 208;   sv = 64;  lov = 256.0f; hiv = 512.0f; }
        else                 { begv = 17008; nl = 56;    sv = 128; lov = 512.0f; hiv = INF_A; }

        const float2 p = reinterpret_cast<const float2*>(loc)[j0];
        int xi = (int)p.x; xi = min(max(xi, 0), WW - 1);
        int yi = (int)p.y; yi = min(max(yi, 0), HH - 1);
        const float mloc = masks[(size_t)b * (HH * WW) + (size_t)yi * WW + xi];
        const bool mpos = mloc > 0.0f;

        float best = FLT_MAX;
        int bi = 0;
        // Descending g: shift-in mask build (constant shifts); `<=` keeps
        // first-occurrence (smallest g) argmin tie-break, values exact.
#pragma unroll 8
        for (int g = GG - 1; g >= 0; --g) {
            const float4 bx = bbx[g];                         // uniform -> s_load
            const bool manyg = ((cmask >> g) & 1ull) != 0ull; // SALU bit test
            const float l  = p.x - bx.x;
            const float t  = p.y - bx.y;
            const float r  = bx.z - p.x;
            const float bt = bx.w - p.y;
            const float mn = fminf(fminf(l, t), fminf(r, bt));
            const float mx = fmaxf(fmaxf(l, t), fmaxf(r, bt));
            const bool in = (mn > 0.0f) && (mpos || !manyg);
            const bool sel = in && (mx >= lov) && (mx <= hiv);
            const float area = (bx.z - bx.x) * (bx.w - bx.y);  // exact, matches ref
            const float la = sel ? area : INF_A;
            if (la <= best) { best = la; bi = g; }
            finmask = (finmask << 1) | (in ? 1ull : 0ull);
        }

        const float4 cb = bbx[bi];  // divergent gather of winning box (L1-hot)
        int label = (best >= INF_A || !mpos) ? NCLS : cls[b * GG + bi];

        row = BB * begv + b * nl + (j0 - begv);

        out[LAB_BASE + row] = (float)label;

        const float inv_s = 1.0f / (float)sv;  // exact pow2 reciprocal
        float4 rg;
        rg.x = (p.x - cb.x) * inv_s;
        rg.y = (p.y - cb.y) * inv_s;
        rg.z = (cb.z - p.x) * inv_s;
        rg.w = (cb.w - p.y) * inv_s;
        reinterpret_cast<float4*>(out + REG_BASE)[row] = rg;

        out[TIND_BASE + row] = (float)((bi + b * GG) * (mpos ? 1 : 0));

        if (label != 0) finmask = 0ull;
    }
    sdat[tid].x = finmask;
    sdat[tid].y = (unsigned long long)row;
    __syncthreads();

    // Coalesced float4 writes of the (nrows x 48) is_in section.
    const int nrows = min(256, NLOC - blockstart);
    const int n4 = nrows * 12;  // 12 float4 per row
    float4* __restrict__ outi = reinterpret_cast<float4*>(out + ISIN_BASE);
    for (int i4 = tid; i4 < n4; i4 += 256) {
        const int lr = i4 / 12;          // magic-mul division
        const int q = i4 - lr * 12;
        const ulonglong2 d = sdat[lr];   // one ds_read_b128 per 4 outputs
        const unsigned int bits = (unsigned int)(d.x >> (q * 4)) & 15u;
        float4 v;
        v.x = (bits & 1u) ? 1.0f : 0.0f;
        v.y = (bits & 2u) ? 1.0f : 0.0f;
        v.z = (bits & 4u) ? 1.0f : 0.0f;
        v.w = (bits & 8u) ? 1.0f : 0.0f;
        outi[(int)d.y * 12 + q] = v;
    }
}

extern "C" void kernel_launch(void* const* d_in, const int* in_sizes, int n_in,
                              void* d_out, int out_size, void* d_ws, size_t ws_size,
                              hipStream_t stream) {
    const float* loc   = (const float*)d_in[0];
    const float* boxes = (const float*)d_in[1];
    const int*   cls   = (const int*)d_in[2];
    const float* masks = (const float*)d_in[3];
    float* out = (float*)d_out;

    dim3 grid((NLOC + 255) / 256, BB);
    assign_kernel<<<grid, 256, 0, stream>>>(loc, boxes, cls, masks, out);
}